// Round 1
// baseline (827.794 us; speedup 1.0000x reference)
//
#include <hip/hip_runtime.h>
#include <stdint.h>

typedef __bf16 bf16_t;
typedef bf16_t bf16x8 __attribute__((ext_vector_type(8)));
typedef float f32x4 __attribute__((ext_vector_type(4)));

#define D_DIM 4096   // K
#define O_DIM 4096   // N
#define M_DIM 16384  // M = 8*2048
#define THRESH 0.05f

// ---------- helpers ----------

__device__ __forceinline__ void gld16(const void* g, void* l) {
  // async global->LDS, 16B per lane; LDS dest must be linear in lane order
  __builtin_amdgcn_global_load_lds(
      (const __attribute__((address_space(1))) uint32_t*)(uintptr_t)g,
      (__attribute__((address_space(3))) uint32_t*)(uint32_t)(uintptr_t)l,
      16, 0, 0);
}

__device__ __forceinline__ unsigned short f2bf(float f) {  // RNE f32->bf16
  uint32_t u = __float_as_uint(f);
  u += 0x7FFFu + ((u >> 16) & 1u);
  return (unsigned short)(u >> 16);
}

__device__ __forceinline__ unsigned short tern(float v) {  // bf16 bits of {-1,0,+1}
  return (__builtin_fabsf(v) < THRESH) ? (unsigned short)0
         : (v > 0.f ? (unsigned short)0x3F80 : (unsigned short)0xBF80);
}

// ---------- pre-pass kernels ----------

// scale partial sums: 512 blocks = 8 d-chunks x 64 col-groups, 256 thr (64 cols x 4 rows)
__global__ void k_scale_part(const float* __restrict__ w, float* __restrict__ part) {
  const int cg = blockIdx.x & 63;
  const int dz = blockIdx.x >> 6;
  const int tx = threadIdx.x & 63;
  const int ty = threadIdx.x >> 6;
  const int o = cg * 64 + tx;
  float s = 0.f;
  const float* p = w + (size_t)(dz * 512 + ty) * O_DIM + o;
  for (int i = 0; i < 128; ++i) {
    s += __builtin_fabsf(*p);
    p += 4 * O_DIM;
  }
  __shared__ float red[4][64];
  red[ty][tx] = s;
  __syncthreads();
  if (ty == 0) part[dz * O_DIM + o] = (red[0][tx] + red[1][tx]) + (red[2][tx] + red[3][tx]);
}

__global__ void k_scale_fin(const float* __restrict__ part, float* __restrict__ scale) {
  const int o = blockIdx.x * 256 + threadIdx.x;
  float s = 0.f;
#pragma unroll
  for (int z = 0; z < 8; ++z) s += part[z * O_DIM + o];
  scale[o] = s * (1.0f / 4096.0f);
}

// ternarize + transpose: w[d][o] f32 -> bt[o][d] bf16 in {-1,0,1}; 64x64 tiles
__global__ void k_tern_t(const float* __restrict__ w, unsigned short* __restrict__ bt) {
  __shared__ __align__(16) unsigned short tile[64][68];  // 136B row stride: 8B-aligned, odd bank stride
  const int ot = blockIdx.x & 63;
  const int dt = blockIdx.x >> 6;
  const int o0 = ot * 64, d0 = dt * 64;
  const int tx = threadIdx.x & 15, ty = threadIdx.x >> 4;
#pragma unroll
  for (int j = 0; j < 4; ++j) {
    const int r = ty + 16 * j;  // d_local
    const float4 v = *(const float4*)&w[(size_t)(d0 + r) * O_DIM + o0 + tx * 4];
    ushort4 u;
    u.x = tern(v.x); u.y = tern(v.y); u.z = tern(v.z); u.w = tern(v.w);
    *(ushort4*)&tile[r][tx * 4] = u;
  }
  __syncthreads();
#pragma unroll
  for (int j = 0; j < 4; ++j) {
    const int orow = ty + 16 * j;  // o_local
    ushort4 u;
    u.x = tile[tx * 4 + 0][orow];
    u.y = tile[tx * 4 + 1][orow];
    u.z = tile[tx * 4 + 2][orow];
    u.w = tile[tx * 4 + 3][orow];
    *(ushort4*)&bt[(size_t)(o0 + orow) * D_DIM + d0 + tx * 4] = u;
  }
}

// x f32 -> bf16 (RNE), 8 elems/thread
__global__ void k_cvt(const float* __restrict__ x, unsigned short* __restrict__ xb) {
  const size_t i = ((size_t)blockIdx.x * 256 + threadIdx.x) * 8;
  const float4 a = *(const float4*)&x[i];
  const float4 b = *(const float4*)&x[i + 4];
  uint4 o;
  o.x = (uint32_t)f2bf(a.x) | ((uint32_t)f2bf(a.y) << 16);
  o.y = (uint32_t)f2bf(a.z) | ((uint32_t)f2bf(a.w) << 16);
  o.z = (uint32_t)f2bf(b.x) | ((uint32_t)f2bf(b.y) << 16);
  o.w = (uint32_t)f2bf(b.z) | ((uint32_t)f2bf(b.w) << 16);
  *(uint4*)&xb[i] = o;
}

// ---------- GEMM: C[m][n] = (sum_k A[m][k]*Bt[n][k]) * scale[n] + bias[n] ----------
// 128x128 tile, BK=32, 256 thr = 4 waves (2x2), 16x16x32 bf16 MFMA, dbuf LDS via global_load_lds

__global__ __launch_bounds__(256, 2) void k_gemm(
    const unsigned short* __restrict__ A,   // [M][K] bf16 bits
    const unsigned short* __restrict__ B,   // [N][K] bf16 bits (ternary)
    const float* __restrict__ scale, const float* __restrict__ bias,
    float* __restrict__ C) {
  __shared__ __align__(16) unsigned short As[2][128 * 32];
  __shared__ __align__(16) unsigned short Bs[2][128 * 32];

  const int bid = blockIdx.x;
  const int wg = (bid & 7) * 512 + (bid >> 3);  // XCD-aware swizzle (4096 % 8 == 0)
  const int mb = wg >> 5, nb = wg & 31;         // N/128 = 32
  const int mBase = mb * 128, nBase = nb * 128;
  const int t = threadIdx.x;
  const int lane = t & 63, wid = t >> 6;
  const int wr = wid >> 1, wc = wid & 1;  // wave 2x2 -> 64x64 subtile each
  const int r16 = lane & 15, kq = lane >> 4;

  // staging: chunk c in [0,512): row=c>>2, k-off=(c&3)*8 bf16 (16B); thread does c=t and c=t+256
  const unsigned short* gA0 = A + (size_t)(mBase + (t >> 2)) * D_DIM + (t & 3) * 8;
  const unsigned short* gA1 = gA0 + (size_t)64 * D_DIM;
  const unsigned short* gB0 = B + (size_t)(nBase + (t >> 2)) * D_DIM + (t & 3) * 8;
  const unsigned short* gB1 = gB0 + (size_t)64 * D_DIM;

  f32x4 acc[4][4] = {};

  const int aoff = (wr * 64 + r16) * 32 + kq * 8;  // A frag: row=l&15, k=8*(l>>4)+j
  const int boff = (wc * 64 + r16) * 32 + kq * 8;  // B frag: col=l&15, k=8*(l>>4)+j

#define STAGE(buf, kt)                              \
  {                                                 \
    const int ko = (kt) * 32;                       \
    gld16(gA0 + ko, &As[buf][t * 8]);               \
    gld16(gA1 + ko, &As[buf][t * 8 + 2048]);        \
    gld16(gB0 + ko, &Bs[buf][t * 8]);               \
    gld16(gB1 + ko, &Bs[buf][t * 8 + 2048]);        \
  }

#define COMPUTE(cb)                                                                     \
  {                                                                                     \
    bf16x8 af[4], bv[4];                                                                \
    _Pragma("unroll") for (int m = 0; m < 4; ++m)                                       \
        af[m] = *(const bf16x8*)&As[cb][aoff + m * (16 * 32)];                          \
    _Pragma("unroll") for (int n = 0; n < 4; ++n)                                       \
        bv[n] = *(const bf16x8*)&Bs[cb][boff + n * (16 * 32)];                          \
    _Pragma("unroll") for (int m = 0; m < 4; ++m)                                       \
      _Pragma("unroll") for (int n = 0; n < 4; ++n)                                     \
          acc[m][n] =                                                                   \
              __builtin_amdgcn_mfma_f32_16x16x32_bf16(af[m], bv[n], acc[m][n], 0, 0, 0);\
  }

  STAGE(0, 0);
  __syncthreads();
  int cur = 0;
  for (int kt = 1; kt < 128; ++kt) {
    STAGE(cur ^ 1, kt);   // prefetch next K-tile into other buffer
    COMPUTE(cur);
    __syncthreads();      // drains vmcnt(0)+lgkmcnt(0): next buffer ready, this one free
    cur ^= 1;
  }
  COMPUTE(cur);

  // epilogue: D row = 4*(l>>4)+r, col = l&15 (verified gfx950 C/D mapping)
#pragma unroll
  for (int n = 0; n < 4; ++n) {
    const int gn = nBase + wc * 64 + n * 16 + r16;
    const float sc = scale[gn];
    const float bb = bias[gn];
#pragma unroll
    for (int m = 0; m < 4; ++m) {
      const int gm0 = mBase + wr * 64 + m * 16 + kq * 4;
#pragma unroll
      for (int r = 0; r < 4; ++r) {
        C[(size_t)(gm0 + r) * O_DIM + gn] = acc[m][n][r] * sc + bb;
      }
    }
  }
#undef STAGE
#undef COMPUTE
}

// ---------- launch ----------

extern "C" void kernel_launch(void* const* d_in, const int* in_sizes, int n_in,
                              void* d_out, int out_size, void* d_ws, size_t ws_size,
                              hipStream_t stream) {
  const float* x = (const float*)d_in[0];    // [8,2048,4096] = [16384][4096]
  const float* w = (const float*)d_in[1];    // [4096][4096]
  const float* bias = (const float*)d_in[2]; // [4096]
  float* out = (float*)d_out;

  // workspace layout
  const size_t XB_OFF = 0;                                   // 16384*4096*2 = 128MB
  const size_t BT_OFF = (size_t)M_DIM * D_DIM * 2;           // 4096*4096*2  = 32MB
  const size_t PART_OFF = BT_OFF + (size_t)O_DIM * D_DIM * 2;// 8*4096*4
  const size_t SCALE_OFF = PART_OFF + 8 * O_DIM * 4;         // 4096*4
  const size_t NEED = SCALE_OFF + O_DIM * 4;
  if (ws_size < NEED) return;  // cannot run correctly; fail loudly without OOB writes

  char* ws = (char*)d_ws;
  unsigned short* xb = (unsigned short*)(ws + XB_OFF);
  unsigned short* bt = (unsigned short*)(ws + BT_OFF);
  float* part = (float*)(ws + PART_OFF);
  float* scale = (float*)(ws + SCALE_OFF);

  k_scale_part<<<512, 256, 0, stream>>>(w, part);
  k_scale_fin<<<16, 256, 0, stream>>>(part, scale);
  k_tern_t<<<64 * 64, 256, 0, stream>>>(w, bt);
  k_cvt<<<(M_DIM * (D_DIM / 8)) / 256, 256, 0, stream>>>(x, xb);
  k_gemm<<<4096, 256, 0, stream>>>(xb, bt, scale, bias, out);
}

// Round 2
// 543.794 us; speedup vs baseline: 1.5223x; 1.5223x over previous
//
#include <hip/hip_runtime.h>
#include <stdint.h>

typedef __bf16 bf16_t;
typedef bf16_t bf16x8 __attribute__((ext_vector_type(8)));
typedef float f32x4 __attribute__((ext_vector_type(4)));

#define D_DIM 4096   // K
#define O_DIM 4096   // N
#define M_DIM 16384  // M
#define THRESH 0.05f

// ---------- helpers ----------

__device__ __forceinline__ void gld16(const void* g, void* l) {
  __builtin_amdgcn_global_load_lds(
      (const __attribute__((address_space(1))) uint32_t*)(uintptr_t)g,
      (__attribute__((address_space(3))) uint32_t*)(uint32_t)(uintptr_t)l,
      16, 0, 0);
}

__device__ __forceinline__ unsigned short f2bf(float f) {  // RNE f32->bf16
  uint32_t u = __float_as_uint(f);
  u += 0x7FFFu + ((u >> 16) & 1u);
  return (unsigned short)(u >> 16);
}

__device__ __forceinline__ unsigned short tern(float v) {  // bf16 bits of {-1,0,+1}
  return (__builtin_fabsf(v) < THRESH) ? (unsigned short)0
         : (v > 0.f ? (unsigned short)0x3F80 : (unsigned short)0xBF80);
}

// ---------- pre-pass kernels (unchanged from round 1, verified) ----------

__global__ void k_scale_part(const float* __restrict__ w, float* __restrict__ part) {
  const int cg = blockIdx.x & 63;
  const int dz = blockIdx.x >> 6;
  const int tx = threadIdx.x & 63;
  const int ty = threadIdx.x >> 6;
  const int o = cg * 64 + tx;
  float s = 0.f;
  const float* p = w + (size_t)(dz * 512 + ty) * O_DIM + o;
  for (int i = 0; i < 128; ++i) {
    s += __builtin_fabsf(*p);
    p += 4 * O_DIM;
  }
  __shared__ float red[4][64];
  red[ty][tx] = s;
  __syncthreads();
  if (ty == 0) part[dz * O_DIM + o] = (red[0][tx] + red[1][tx]) + (red[2][tx] + red[3][tx]);
}

__global__ void k_scale_fin(const float* __restrict__ part, float* __restrict__ scale) {
  const int o = blockIdx.x * 256 + threadIdx.x;
  float s = 0.f;
#pragma unroll
  for (int z = 0; z < 8; ++z) s += part[z * O_DIM + o];
  scale[o] = s * (1.0f / 4096.0f);
}

__global__ void k_tern_t(const float* __restrict__ w, unsigned short* __restrict__ bt) {
  __shared__ __align__(16) unsigned short tile[64][68];
  const int ot = blockIdx.x & 63;
  const int dt = blockIdx.x >> 6;
  const int o0 = ot * 64, d0 = dt * 64;
  const int tx = threadIdx.x & 15, ty = threadIdx.x >> 4;
#pragma unroll
  for (int j = 0; j < 4; ++j) {
    const int r = ty + 16 * j;
    const float4 v = *(const float4*)&w[(size_t)(d0 + r) * O_DIM + o0 + tx * 4];
    ushort4 u;
    u.x = tern(v.x); u.y = tern(v.y); u.z = tern(v.z); u.w = tern(v.w);
    *(ushort4*)&tile[r][tx * 4] = u;
  }
  __syncthreads();
#pragma unroll
  for (int j = 0; j < 4; ++j) {
    const int orow = ty + 16 * j;
    ushort4 u;
    u.x = tile[tx * 4 + 0][orow];
    u.y = tile[tx * 4 + 1][orow];
    u.z = tile[tx * 4 + 2][orow];
    u.w = tile[tx * 4 + 3][orow];
    *(ushort4*)&bt[(size_t)(o0 + orow) * D_DIM + d0 + tx * 4] = u;
  }
}

__global__ void k_cvt(const float* __restrict__ x, unsigned short* __restrict__ xb) {
  const size_t i = ((size_t)blockIdx.x * 256 + threadIdx.x) * 8;
  const float4 a = *(const float4*)&x[i];
  const float4 b = *(const float4*)&x[i + 4];
  uint4 o;
  o.x = (uint32_t)f2bf(a.x) | ((uint32_t)f2bf(a.y) << 16);
  o.y = (uint32_t)f2bf(a.z) | ((uint32_t)f2bf(a.w) << 16);
  o.z = (uint32_t)f2bf(b.x) | ((uint32_t)f2bf(b.y) << 16);
  o.w = (uint32_t)f2bf(b.z) | ((uint32_t)f2bf(b.w) << 16);
  *(uint4*)&xb[i] = o;
}

// ---------- 256x256 8-phase GEMM ----------
// C[m][n] = (sum_k A[m][k]*Bt[n][k]) * scale[n] + bias[n]
// BM=BN=256, BK=64, 512 thr = 8 waves (2Mx4N), per-wave C = 128x64.
// LDS 128KB: A = 2dbuf x 2half x [128][64] bf16; B same, at +64KB.
// Conflict-free layout: LDS granule q=row*8+(g^(row&7)) holds global granule
// (row, g); staged via pre-swizzled GLOBAL address (gld_lds dest linear).
// Read: byte = row*128 + ((kq^(r16&7))<<4) ^ (kk<<6)  -> 2 lanes/bank (free).

#define BAR() __builtin_amdgcn_s_barrier()
#define LGKM0()                                         \
  do {                                                  \
    asm volatile("s_waitcnt lgkmcnt(0)" ::: "memory");  \
    __builtin_amdgcn_sched_barrier(0);                  \
  } while (0)
#define VMW(n) asm volatile("s_waitcnt vmcnt(" #n ")" ::: "memory")

#define STAGE_A(d, h, ktv)                                                   \
  do {                                                                       \
    gld16(pA##h##_0 + (ktv) * 64, smem + (d)*32768 + (h)*16384 + t * 16);    \
    gld16(pA##h##_1 + (ktv) * 64,                                            \
          smem + (d)*32768 + (h)*16384 + 8192 + t * 16);                     \
  } while (0)
#define STAGE_B(d, h, ktv)                                                   \
  do {                                                                       \
    gld16(pB##h##_0 + (ktv) * 64,                                            \
          smem + 65536 + (d)*32768 + (h)*16384 + t * 16);                    \
    gld16(pB##h##_1 + (ktv) * 64,                                            \
          smem + 65536 + (d)*32768 + (h)*16384 + 8192 + t * 16);             \
  } while (0)

#define READ_A(d, mh)                                                \
  do {                                                               \
    const char* ab_ = smem + (d)*32768 + wr * 16384 + (mh)*8192;     \
    _Pragma("unroll") for (int m4 = 0; m4 < 4; ++m4) {               \
      aq[0][m4] = *(const bf16x8*)(ab_ + m4 * 2048 + aLane);         \
      aq[1][m4] = *(const bf16x8*)(ab_ + m4 * 2048 + (aLane ^ 64));  \
    }                                                                \
  } while (0)
#define READ_B(d, nh)                                                      \
  do {                                                                     \
    const char* bb_ = smem + 65536 + (d)*32768 + hb * 16384 +              \
                      ((wc & 1) * 8192) + (nh)*4096;                       \
    _Pragma("unroll") for (int n2 = 0; n2 < 2; ++n2) {                     \
      bq[nh][0][n2] = *(const bf16x8*)(bb_ + n2 * 2048 + aLane);           \
      bq[nh][1][n2] = *(const bf16x8*)(bb_ + n2 * 2048 + (aLane ^ 64));    \
    }                                                                      \
  } while (0)

#define MFMA_Q(mh, nh)                                                        \
  do {                                                                        \
    __builtin_amdgcn_s_setprio(1);                                            \
    _Pragma("unroll") for (int kk = 0; kk < 2; ++kk)                          \
    _Pragma("unroll") for (int m4 = 0; m4 < 4; ++m4)                          \
    _Pragma("unroll") for (int n2 = 0; n2 < 2; ++n2)                          \
        acc[(mh)*4 + m4][(nh)*2 + n2] =                                       \
            __builtin_amdgcn_mfma_f32_16x16x32_bf16(                          \
                aq[kk][m4], bq[nh][kk][n2], acc[(mh)*4 + m4][(nh)*2 + n2],    \
                0, 0, 0);                                                     \
    __builtin_amdgcn_s_setprio(0);                                            \
  } while (0)

__global__ __launch_bounds__(512, 2) void k_gemm8(
    const unsigned short* __restrict__ A,   // [M][K] bf16 bits
    const unsigned short* __restrict__ B,   // [N][K] bf16 bits (ternary)
    const float* __restrict__ scale, const float* __restrict__ bias,
    float* __restrict__ C) {
  __shared__ __align__(16) char smem[131072];

  const int bid = blockIdx.x;
  const int wg = (bid & 7) * 128 + (bid >> 3);  // XCD swizzle, 1024%8==0
  const int mb = wg >> 4, nb = wg & 15;         // 64 x 16 blocks
  const int mBase = mb * 256, nBase = nb * 256;

  const int t = threadIdx.x;
  const int lane = t & 63, wid = t >> 6;
  const int wr = wid >> 2, wc = wid & 3;  // 2 x 4 waves
  const int hb = wc >> 1;                 // B half this wave reads
  const int r16 = lane & 15, kq = lane >> 4;
  const int aLane = r16 * 128 + ((kq ^ (lane & 7)) << 4);

  // staging: thread t stages granules q0=t, q1=512+t of each half-tile
  const int q1 = 512 + t;
  const int sr0 = t >> 3, sg0 = (t & 7) ^ (sr0 & 7);
  const int sr1 = q1 >> 3, sg1 = (q1 & 7) ^ (sr1 & 7);

  const unsigned short* pA0_0 = A + (size_t)(mBase + sr0) * D_DIM + sg0 * 8;
  const unsigned short* pA0_1 = A + (size_t)(mBase + sr1) * D_DIM + sg1 * 8;
  const unsigned short* pA1_0 = A + (size_t)(mBase + 128 + sr0) * D_DIM + sg0 * 8;
  const unsigned short* pA1_1 = A + (size_t)(mBase + 128 + sr1) * D_DIM + sg1 * 8;
  const unsigned short* pB0_0 = B + (size_t)(nBase + sr0) * D_DIM + sg0 * 8;
  const unsigned short* pB0_1 = B + (size_t)(nBase + sr1) * D_DIM + sg1 * 8;
  const unsigned short* pB1_0 = B + (size_t)(nBase + 128 + sr0) * D_DIM + sg0 * 8;
  const unsigned short* pB1_1 = B + (size_t)(nBase + 128 + sr1) * D_DIM + sg1 * 8;

  f32x4 acc[8][4] = {};
  bf16x8 aq[2][4], bq[2][2][2];

  // prologue: S(0) fully (first 4 stages), then S(1).B0,B1
  STAGE_B(0, 0, 0); STAGE_B(0, 1, 0); STAGE_A(0, 0, 0); STAGE_A(0, 1, 0);
  STAGE_B(1, 0, 1); STAGE_B(1, 1, 1);
  VMW(4);  // 12 ops issued, <=4 outstanding -> S(0)'s 8 ops done
  BAR();

  for (int kt = 0; kt < 62; kt += 2) {
    // p0: kt (buf0) quad (0,0); issue S(kt+1).A0 -> buf1
    READ_A(0, 0); READ_B(0, 0); STAGE_A(1, 0, kt + 1);
    BAR(); LGKM0(); MFMA_Q(0, 0); BAR();
    // p1: quad (0,1); issue S(kt+1).A1
    READ_B(0, 1); STAGE_A(1, 1, kt + 1);
    BAR(); LGKM0(); MFMA_Q(0, 1); BAR();
    // p2: quad (1,0); issue S(kt+2).B0 -> buf0 (kt's B reads done p0/p1)
    READ_A(0, 1); STAGE_B(0, 0, kt + 2);
    BAR(); LGKM0(); MFMA_Q(1, 0); BAR();
    // p3: quad (1,1); issue S(kt+2).B1; K-tile boundary wait
    STAGE_B(0, 1, kt + 2);
    BAR(); LGKM0(); MFMA_Q(1, 1); VMW(4); BAR();
    // p4: kt+1 (buf1) quad (0,0); issue S(kt+2).A0 (kt's A reads done p0/p2)
    READ_A(1, 0); READ_B(1, 0); STAGE_A(0, 0, kt + 2);
    BAR(); LGKM0(); MFMA_Q(0, 0); BAR();
    // p5: quad (0,1); issue S(kt+2).A1
    READ_B(1, 1); STAGE_A(0, 1, kt + 2);
    BAR(); LGKM0(); MFMA_Q(0, 1); BAR();
    // p6: quad (1,0); issue S(kt+3).B0 -> buf1 (kt+1's B reads done p4/p5)
    READ_A(1, 1); STAGE_B(1, 0, kt + 3);
    BAR(); LGKM0(); MFMA_Q(1, 0); BAR();
    // p7: quad (1,1); issue S(kt+3).B1; boundary wait
    STAGE_B(1, 1, kt + 3);
    BAR(); LGKM0(); MFMA_Q(1, 1); VMW(4); BAR();
  }

  // peeled final iteration: kt=62 (buf0), kt=63 (buf1); drain waits 4 -> 0
  READ_A(0, 0); READ_B(0, 0); STAGE_A(1, 0, 63);
  BAR(); LGKM0(); MFMA_Q(0, 0); BAR();
  READ_B(0, 1); STAGE_A(1, 1, 63);
  BAR(); LGKM0(); MFMA_Q(0, 1); BAR();
  READ_A(0, 1);
  BAR(); LGKM0(); MFMA_Q(1, 0); BAR();
  BAR(); LGKM0(); MFMA_Q(1, 1); VMW(0); BAR();
  READ_A(1, 0); READ_B(1, 0);
  BAR(); LGKM0(); MFMA_Q(0, 0); BAR();
  READ_B(1, 1);
  BAR(); LGKM0(); MFMA_Q(0, 1); BAR();
  READ_A(1, 1);
  BAR(); LGKM0(); MFMA_Q(1, 0); BAR();
  LGKM0(); MFMA_Q(1, 1);

  // epilogue: C/D mapping col=lane&15, row=4*(lane>>4)+r (verified r1)
#pragma unroll
  for (int ni = 0; ni < 4; ++ni) {
    const int gc = nBase + wc * 64 + ni * 16 + r16;
    const float sc = scale[gc];
    const float bb = bias[gc];
#pragma unroll
    for (int mi = 0; mi < 8; ++mi) {
      const int gr0 = mBase + wr * 128 + mi * 16 + kq * 4;
#pragma unroll
      for (int r = 0; r < 4; ++r) {
        C[(size_t)(gr0 + r) * O_DIM + gc] = acc[mi][ni][r] * sc + bb;
      }
    }
  }
}

// ---------- launch ----------

extern "C" void kernel_launch(void* const* d_in, const int* in_sizes, int n_in,
                              void* d_out, int out_size, void* d_ws, size_t ws_size,
                              hipStream_t stream) {
  const float* x = (const float*)d_in[0];
  const float* w = (const float*)d_in[1];
  const float* bias = (const float*)d_in[2];
  float* out = (float*)d_out;

  const size_t XB_OFF = 0;
  const size_t BT_OFF = (size_t)M_DIM * D_DIM * 2;
  const size_t PART_OFF = BT_OFF + (size_t)O_DIM * D_DIM * 2;
  const size_t SCALE_OFF = PART_OFF + 8 * O_DIM * 4;
  const size_t NEED = SCALE_OFF + O_DIM * 4;
  if (ws_size < NEED) return;

  char* ws = (char*)d_ws;
  unsigned short* xb = (unsigned short*)(ws + XB_OFF);
  unsigned short* bt = (unsigned short*)(ws + BT_OFF);
  float* part = (float*)(ws + PART_OFF);
  float* scale = (float*)(ws + SCALE_OFF);

  k_scale_part<<<512, 256, 0, stream>>>(w, part);
  k_scale_fin<<<16, 256, 0, stream>>>(part, scale);
  k_tern_t<<<64 * 64, 256, 0, stream>>>(w, bt);
  k_cvt<<<(M_DIM * (D_DIM / 8)) / 256, 256, 0, stream>>>(x, xb);
  k_gemm8<<<1024, 512, 0, stream>>>(xb, bt, scale, bias, out);
}